// Round 4
// baseline (151.675 us; speedup 1.0000x reference)
//
#include <hip/hip_runtime.h>
#include <hip/hip_cooperative_groups.h>
namespace cg = cooperative_groups;

#define M_ 8
#define D1_ 32
#define D2_ 32
#define E_ 256
#define K_ 2
#define L_ 16384
#define NSPECIAL_ 32
#define SIDX_ 8
#define NPLAYERS_ 4
#define H_ 256
#define P_ (D1_ * D2_)            // 1024 positions per batch elem
#define POL_COLS (L_ + SIDX_)     // 16392

#define NCHUNK 16                 // e-chunks for hidden-layer partials
#define CHUNK_E (E_ / NCHUNK)     // 16 e's per chunk

// ws layout (floats)
#define WS_A 0
#define WS_B (M_ * P_)                    // 8192
#define WS_BASE (2 * M_ * P_)             // 16384
#define WS_PART (2 * M_ * P_ + 256)       // 16640, partials: 2*8*16*256 = 65536 f
#define WS_NEED_BYTES ((WS_PART + 2 * M_ * NCHUNK * H_) * 4)

#define GRID_ 528                 // 512 policy blocks + 16 head blocks
#define NJOB_AB 512               // 16 emb rows per job (4 waves x 4 rows)
#define JOB_BASE 512
#define NJOBA 769                 // 512 AB + 1 base + 256 partials

// ---------------------------------------------------------------------------
// Single cooperative kernel.
// Phase A (grid-stride over 769 jobs):
//   job < 512 : A/B tables, 16 rows/job. Wave handles 4 rows (16 lanes/row,
//               float4/lane, 4 chunks) -> 8 width-16 shuffles per 4 rows.
//   job == 512: base[m] = dot(cls[m], Wp[512:768]) + bp (2 waves, 4 m each)
//   job > 512 : hidden-layer partials, thread-per-h, one 16-e chunk/block-job
// grid.sync()
// Phase B: blk<512 -> policy fill (LDS-staged tables); else 16 head blocks.
// ---------------------------------------------------------------------------
__global__ __launch_bounds__(256) void k_pv_coop(
    const float* __restrict__ emb, const float* __restrict__ cls,
    const int* __restrict__ sm, const int* __restrict__ sidx,
    const float* __restrict__ Wp, const float* __restrict__ bp,
    const float* __restrict__ Ws1, const float* __restrict__ Wv1,
    const float* __restrict__ bs1, const float* __restrict__ bv1,
    const float* __restrict__ Ws2, const float* __restrict__ bs2,
    const float* __restrict__ Wv2, const float* __restrict__ bv2,
    float* __restrict__ ws, float* __restrict__ out)
{
    __shared__ float sh[2 * P_ + 64];
    const int t = threadIdx.x;
    const int wave = t >> 6, lane = t & 63;
    const int sub = lane >> 4, li = lane & 15;   // 4 row-groups of 16 lanes

    // ---------------- Phase A ----------------
    for (int job = blockIdx.x; job < NJOBA; job += GRID_) {
        if (job < NJOB_AB) {
            const int row = job * 16 + wave * 4 + sub;
            const float* __restrict__ rp = emb + (size_t)row * E_;
            float a = 0.f, b = 0.f;
            #pragma unroll
            for (int it = 0; it < 4; ++it) {
                const float4 v  = ((const float4*)rp)[li + 16 * it];
                const float4 w0 = ((const float4*)Wp)[li + 16 * it];
                const float4 w1 = ((const float4*)(Wp + E_))[li + 16 * it];
                a += v.x * w0.x + v.y * w0.y + v.z * w0.z + v.w * w0.w;
                b += v.x * w1.x + v.y * w1.y + v.z * w1.z + v.w * w1.w;
            }
            #pragma unroll
            for (int off = 8; off > 0; off >>= 1) {
                a += __shfl_down(a, off, 16);
                b += __shfl_down(b, off, 16);
            }
            if (li == 0) { ws[WS_A + row] = a; ws[WS_B + row] = b; }
        } else if (job == JOB_BASE) {
            if (wave < 2) {
                const int m = wave * 4 + sub;
                const float* __restrict__ rp = cls + (size_t)m * E_;
                float a = 0.f;
                #pragma unroll
                for (int it = 0; it < 4; ++it) {
                    const float4 v = ((const float4*)rp)[li + 16 * it];
                    const float4 w = ((const float4*)(Wp + 2 * E_))[li + 16 * it];
                    a += v.x * w.x + v.y * w.y + v.z * w.z + v.w * w.w;
                }
                #pragma unroll
                for (int off = 8; off > 0; off >>= 1) a += __shfl_down(a, off, 16);
                if (li == 0) ws[WS_BASE + m] = a + bp[0];
            }
        } else {
            const int idx  = job - JOB_BASE - 1;   // 0..255
            const int head = idx >> 7;             // 0 = special, 1 = value
            const int rem  = idx & 127;
            const int m    = rem >> 4;
            const int c    = rem & 15;
            const float* __restrict__ W1 = head ? Wv1 : Ws1;
            const int e0 = c * CHUNK_E;
            const float* __restrict__ cm = cls + (size_t)m * E_ + e0;
            float acc = 0.f;
            #pragma unroll
            for (int i = 0; i < CHUNK_E; ++i)
                acc = fmaf(cm[i], W1[(size_t)(e0 + i) * H_ + t], acc);
            ws[WS_PART + (size_t)((head * M_ + m) * NCHUNK + c) * H_ + t] = acc;
        }
    }

    cg::this_grid().sync();

    // ---------------- Phase B ----------------
    const int blk = blockIdx.x;
    if (blk < 512) {
        float* As = sh;
        float* Bs = sh + P_;
        const int m = blk >> 6;
        ((float4*)As)[t] = ((const float4*)(ws + WS_A + (size_t)m * P_))[t];
        ((float4*)Bs)[t] = ((const float4*)(ws + WS_B + (size_t)m * P_))[t];
        const float bm = ws[WS_BASE + m];
        __syncthreads();
        const int l = ((blk & 63) << 8) + t;
        const int4 s = ((const int4*)sm)[l];
        out[(size_t)m * POL_COLS + l] = As[s.x * D2_ + s.y] + Bs[s.z * D2_ + s.w] + bm;
    } else {
        float* hid = sh;
        float* red = sh + H_;
        float* sp  = sh + 2 * H_;
        const int idx  = blk - 512;
        const int head = idx >> 3;     // 0 = special, 1 = value
        const int m    = idx & 7;

        float acc = head ? bv1[t] : bs1[t];
        const float* __restrict__ pb =
            ws + WS_PART + (size_t)((head * M_ + m) * NCHUNK) * H_ + t;
        #pragma unroll
        for (int c = 0; c < NCHUNK; ++c) acc += pb[c * H_];
        hid[t] = fmaxf(acc, 0.f);
        __syncthreads();

        if (head == 0) {
            const int ns = t & 31, c = t >> 5;
            float p = 0.f;
            #pragma unroll
            for (int i = 0; i < 32; ++i) {
                const int h = c * 32 + i;
                p = fmaf(hid[h], Ws2[(size_t)h * NSPECIAL_ + ns], p);
            }
            red[t] = p;
            __syncthreads();
            if (t < NSPECIAL_) {
                float s = bs2[t];
                #pragma unroll
                for (int c2 = 0; c2 < 8; ++c2) s += red[c2 * 32 + t];
                sp[t] = s;
            }
            __syncthreads();
            if (t < SIDX_)
                out[(size_t)m * POL_COLS + L_ + t] = sp[sidx[t]];
        } else {
            if (t < 128) {
                const int np = t & 3, c = t >> 2;
                float p = 0.f;
                #pragma unroll
                for (int i = 0; i < 8; ++i) {
                    const int h = c * 8 + i;
                    p = fmaf(hid[h], Wv2[(size_t)h * NPLAYERS_ + np], p);
                }
                red[t] = p;
            }
            __syncthreads();
            if (t < NPLAYERS_) {
                float s = bv2[t];
                #pragma unroll
                for (int c2 = 0; c2 < 32; ++c2) s += red[c2 * 4 + t];
                out[(size_t)M_ * POL_COLS + (size_t)m * NPLAYERS_ + t] = s;
            }
        }
    }
}

// ---------------------------------------------------------------------------
// Fallback: round-3 two-kernel path (used if cooperative enqueue fails).
// ---------------------------------------------------------------------------
__global__ __launch_bounds__(256) void k_fused1(
    const float* __restrict__ emb, const float* __restrict__ cls,
    const float* __restrict__ Wp, const float* __restrict__ bp,
    const float* __restrict__ Ws1, const float* __restrict__ Wv1,
    float* __restrict__ ws)
{
    const int blk = blockIdx.x;
    const int tid = threadIdx.x;

    if (blk < 2048) {
        const int wave = tid >> 6, lane = tid & 63;
        const int b = blk * 4 + wave;
        const float4 v  = ((const float4*)(emb + (size_t)b * E_))[lane];
        const float4 w0 = ((const float4*)(Wp))[lane];
        const float4 w1 = ((const float4*)(Wp + E_))[lane];
        float a  = v.x * w0.x + v.y * w0.y + v.z * w0.z + v.w * w0.w;
        float bb = v.x * w1.x + v.y * w1.y + v.z * w1.z + v.w * w1.w;
        #pragma unroll
        for (int off = 32; off > 0; off >>= 1) {
            a  += __shfl_down(a,  off, 64);
            bb += __shfl_down(bb, off, 64);
        }
        if (lane == 0) { ws[WS_A + b] = a; ws[WS_B + b] = bb; }
    } else if (blk < 2050) {
        const int wave = tid >> 6, lane = tid & 63;
        const int m = (blk - 2048) * 4 + wave;
        const float4 v = ((const float4*)(cls + (size_t)m * E_))[lane];
        const float4 w = ((const float4*)(Wp + 2 * E_))[lane];
        float a = v.x * w.x + v.y * w.y + v.z * w.z + v.w * w.w;
        #pragma unroll
        for (int off = 32; off > 0; off >>= 1) a += __shfl_down(a, off, 64);
        if (lane == 0) ws[WS_BASE + m] = a + bp[0];
    } else {
        const int idx  = blk - 2050;
        const int head = idx >> 7;
        const int rem  = idx & 127;
        const int m    = rem >> 4;
        const int c    = rem & 15;
        const float* __restrict__ W1 = head ? Wv1 : Ws1;
        const int e0 = c * CHUNK_E;
        const float* __restrict__ cm = cls + (size_t)m * E_ + e0;
        float acc = 0.f;
        #pragma unroll
        for (int i = 0; i < CHUNK_E; ++i)
            acc = fmaf(cm[i], W1[(size_t)(e0 + i) * H_ + tid], acc);
        ws[WS_PART + (size_t)((head * M_ + m) * NCHUNK + c) * H_ + tid] = acc;
    }
}

__global__ __launch_bounds__(256) void k_fused2(
    const int* __restrict__ sm, const float* __restrict__ ws,
    const int* __restrict__ sidx,
    const float* __restrict__ bs1, const float* __restrict__ bv1,
    const float* __restrict__ Ws2, const float* __restrict__ bs2,
    const float* __restrict__ Wv2, const float* __restrict__ bv2,
    float* __restrict__ out)
{
    __shared__ float sh[2 * P_ + 64];
    const int blk = blockIdx.x;
    const int t = threadIdx.x;

    if (blk < 512) {
        float* As = sh;
        float* Bs = sh + P_;
        const int m = blk >> 6;
        ((float4*)As)[t] = ((const float4*)(ws + WS_A + (size_t)m * P_))[t];
        ((float4*)Bs)[t] = ((const float4*)(ws + WS_B + (size_t)m * P_))[t];
        const float bm = ws[WS_BASE + m];
        __syncthreads();
        const int l = ((blk & 63) << 8) + t;
        const int4 s = ((const int4*)sm)[l];
        out[(size_t)m * POL_COLS + l] = As[s.x * D2_ + s.y] + Bs[s.z * D2_ + s.w] + bm;
    } else {
        float* hid = sh;
        float* red = sh + H_;
        float* sp  = sh + 2 * H_;
        const int idx  = blk - 512;
        const int head = idx >> 3;
        const int m    = idx & 7;

        float acc = head ? bv1[t] : bs1[t];
        const float* __restrict__ pb =
            ws + WS_PART + (size_t)((head * M_ + m) * NCHUNK) * H_ + t;
        #pragma unroll
        for (int c = 0; c < NCHUNK; ++c) acc += pb[c * H_];
        hid[t] = fmaxf(acc, 0.f);
        __syncthreads();

        if (head == 0) {
            const int ns = t & 31, c = t >> 5;
            float p = 0.f;
            #pragma unroll
            for (int i = 0; i < 32; ++i) {
                const int h = c * 32 + i;
                p = fmaf(hid[h], Ws2[(size_t)h * NSPECIAL_ + ns], p);
            }
            red[t] = p;
            __syncthreads();
            if (t < NSPECIAL_) {
                float s = bs2[t];
                #pragma unroll
                for (int c2 = 0; c2 < 8; ++c2) s += red[c2 * 32 + t];
                sp[t] = s;
            }
            __syncthreads();
            if (t < SIDX_)
                out[(size_t)m * POL_COLS + L_ + t] = sp[sidx[t]];
        } else {
            if (t < 128) {
                const int np = t & 3, c = t >> 2;
                float p = 0.f;
                #pragma unroll
                for (int i = 0; i < 8; ++i) {
                    const int h = c * 8 + i;
                    p = fmaf(hid[h], Wv2[(size_t)h * NPLAYERS_ + np], p);
                }
                red[t] = p;
            }
            __syncthreads();
            if (t < NPLAYERS_) {
                float s = bv2[t];
                #pragma unroll
                for (int c2 = 0; c2 < 32; ++c2) s += red[c2 * 4 + t];
                out[(size_t)M_ * POL_COLS + (size_t)m * NPLAYERS_ + t] = s;
            }
        }
    }
}

extern "C" void kernel_launch(void* const* d_in, const int* in_sizes, int n_in,
                              void* d_out, int out_size, void* d_ws, size_t ws_size,
                              hipStream_t stream) {
    const float* emb  = (const float*)d_in[0];
    const float* cls  = (const float*)d_in[1];
    const int*   sm   = (const int*)d_in[2];
    const int*   sidx = (const int*)d_in[3];
    const float* Wp   = (const float*)d_in[4];
    const float* bp   = (const float*)d_in[5];
    const float* Wv1  = (const float*)d_in[6];
    const float* bv1  = (const float*)d_in[7];
    const float* Wv2  = (const float*)d_in[8];
    const float* bv2  = (const float*)d_in[9];
    const float* Ws1  = (const float*)d_in[10];
    const float* bs1  = (const float*)d_in[11];
    const float* Ws2  = (const float*)d_in[12];
    const float* bs2  = (const float*)d_in[13];
    float* out = (float*)d_out;
    float* ws  = (float*)d_ws;

    hipError_t err = hipErrorUnknown;
    if (ws_size >= (size_t)WS_NEED_BYTES) {
        void* args[] = {
            (void*)&emb, (void*)&cls, (void*)&sm, (void*)&sidx,
            (void*)&Wp,  (void*)&bp,  (void*)&Ws1, (void*)&Wv1,
            (void*)&bs1, (void*)&bv1, (void*)&Ws2, (void*)&bs2,
            (void*)&Wv2, (void*)&bv2, (void*)&ws,  (void*)&out };
        err = hipLaunchCooperativeKernel((const void*)k_pv_coop,
                                         dim3(GRID_), dim3(256),
                                         args, 0, stream);
    }
    if (err != hipSuccess && ws_size >= (size_t)WS_NEED_BYTES) {
        k_fused1<<<2050 + 2 * M_ * NCHUNK, 256, 0, stream>>>(
            emb, cls, Wp, bp, Ws1, Wv1, ws);
        k_fused2<<<512 + 16, 256, 0, stream>>>(
            sm, ws, sidx, bs1, bv1, Ws2, bs2, Wv2, bv2, out);
    }
}

// Round 6
// 85.195 us; speedup vs baseline: 1.7803x; 1.7803x over previous
//
#include <hip/hip_runtime.h>

#define M_ 8
#define D1_ 32
#define D2_ 32
#define E_ 256
#define K_ 2
#define L_ 16384
#define NSPECIAL_ 32
#define SIDX_ 8
#define NPLAYERS_ 4
#define H_ 256
#define P_ (D1_ * D2_)            // 1024 positions per batch elem
#define POL_COLS (L_ + SIDX_)     // 16392

#define NCHUNK 16                 // e-chunks for hidden-layer partials
#define CHUNK_E (E_ / NCHUNK)     // 16 e's per chunk

// ws layout (floats)
#define WS_A 0
#define WS_B (M_ * P_)                    // 8192
#define WS_BASE (2 * M_ * P_)             // 16384
#define WS_PART (2 * M_ * P_ + 256)       // 16640, partials: 2*8*16*256 = 65536 f
#define WS_NEED_BYTES ((WS_PART + 2 * M_ * NCHUNK * H_) * 4)

#define NJOB_AB 512               // 16 emb rows per job (4 waves x 4 rows)
#define JOB_BASE 512
#define NJOBA 769                 // 512 AB + 1 base + 256 partials

// ---------------------------------------------------------------------------
// K1: one block per job (769 blocks, no grid-stride).
//   job < 512 : A/B tables, 16 rows/job. Wave handles 4 rows (16 lanes/row,
//               float4/lane, 4 chunks) -> 8 width-16 shuffles per 4 rows.
//   job == 512: base[m] = dot(cls[m], Wp[512:768]) + bp (2 waves, 4 m each)
//   job > 512 : hidden-layer partials, thread-per-h, one 16-e chunk per job
// ---------------------------------------------------------------------------
__global__ __launch_bounds__(256) void k_build(
    const float* __restrict__ emb, const float* __restrict__ cls,
    const float* __restrict__ Wp, const float* __restrict__ bp,
    const float* __restrict__ Ws1, const float* __restrict__ Wv1,
    float* __restrict__ ws)
{
    const int t = threadIdx.x;
    const int wave = t >> 6, lane = t & 63;
    const int sub = lane >> 4, li = lane & 15;   // 4 row-groups of 16 lanes
    const int job = blockIdx.x;

    if (job < NJOB_AB) {
        const int row = job * 16 + wave * 4 + sub;
        const float* __restrict__ rp = emb + (size_t)row * E_;
        float a = 0.f, b = 0.f;
        #pragma unroll
        for (int it = 0; it < 4; ++it) {
            const float4 v  = ((const float4*)rp)[li + 16 * it];
            const float4 w0 = ((const float4*)Wp)[li + 16 * it];
            const float4 w1 = ((const float4*)(Wp + E_))[li + 16 * it];
            a += v.x * w0.x + v.y * w0.y + v.z * w0.z + v.w * w0.w;
            b += v.x * w1.x + v.y * w1.y + v.z * w1.z + v.w * w1.w;
        }
        #pragma unroll
        for (int off = 8; off > 0; off >>= 1) {
            a += __shfl_down(a, off, 16);
            b += __shfl_down(b, off, 16);
        }
        if (li == 0) { ws[WS_A + row] = a; ws[WS_B + row] = b; }
    } else if (job == JOB_BASE) {
        if (wave < 2) {
            const int m = wave * 4 + sub;
            const float* __restrict__ rp = cls + (size_t)m * E_;
            float a = 0.f;
            #pragma unroll
            for (int it = 0; it < 4; ++it) {
                const float4 v = ((const float4*)rp)[li + 16 * it];
                const float4 w = ((const float4*)(Wp + 2 * E_))[li + 16 * it];
                a += v.x * w.x + v.y * w.y + v.z * w.z + v.w * w.w;
            }
            #pragma unroll
            for (int off = 8; off > 0; off >>= 1) a += __shfl_down(a, off, 16);
            if (li == 0) ws[WS_BASE + m] = a + bp[0];
        }
    } else {
        const int idx  = job - JOB_BASE - 1;   // 0..255
        const int head = idx >> 7;             // 0 = special, 1 = value
        const int rem  = idx & 127;
        const int m    = rem >> 4;
        const int c    = rem & 15;
        const float* __restrict__ W1 = head ? Wv1 : Ws1;
        const int e0 = c * CHUNK_E;
        const float* __restrict__ cm = cls + (size_t)m * E_ + e0;
        float acc = 0.f;
        #pragma unroll
        for (int i = 0; i < CHUNK_E; ++i)
            acc = fmaf(cm[i], W1[(size_t)(e0 + i) * H_ + t], acc);
        ws[WS_PART + (size_t)((head * M_ + m) * NCHUNK + c) * H_ + t] = acc;
    }
}

// ---------------------------------------------------------------------------
// K2: [0,512)   policy fill with LDS-staged A/B tables
//     [512,528) head second layer: reduce partials + relu + GEMV
// (byte-identical logic to the round-3 kernel that passed)
// ---------------------------------------------------------------------------
__global__ __launch_bounds__(256) void k_fused2(
    const int* __restrict__ sm, const float* __restrict__ ws,
    const int* __restrict__ sidx,
    const float* __restrict__ bs1, const float* __restrict__ bv1,
    const float* __restrict__ Ws2, const float* __restrict__ bs2,
    const float* __restrict__ Wv2, const float* __restrict__ bv2,
    float* __restrict__ out)
{
    __shared__ float sh[2 * P_ + 64];
    const int blk = blockIdx.x;
    const int t = threadIdx.x;

    if (blk < 512) {
        float* As = sh;
        float* Bs = sh + P_;
        const int m = blk >> 6;
        ((float4*)As)[t] = ((const float4*)(ws + WS_A + (size_t)m * P_))[t];
        ((float4*)Bs)[t] = ((const float4*)(ws + WS_B + (size_t)m * P_))[t];
        const float bm = ws[WS_BASE + m];
        __syncthreads();
        const int l = ((blk & 63) << 8) + t;
        const int4 s = ((const int4*)sm)[l];
        out[(size_t)m * POL_COLS + l] = As[s.x * D2_ + s.y] + Bs[s.z * D2_ + s.w] + bm;
    } else {
        float* hid = sh;
        float* red = sh + H_;
        float* sp  = sh + 2 * H_;
        const int idx  = blk - 512;
        const int head = idx >> 3;     // 0 = special, 1 = value
        const int m    = idx & 7;

        float acc = head ? bv1[t] : bs1[t];
        const float* __restrict__ pb =
            ws + WS_PART + (size_t)((head * M_ + m) * NCHUNK) * H_ + t;
        #pragma unroll
        for (int c = 0; c < NCHUNK; ++c) acc += pb[c * H_];
        hid[t] = fmaxf(acc, 0.f);
        __syncthreads();

        if (head == 0) {
            const int ns = t & 31, c = t >> 5;
            float p = 0.f;
            #pragma unroll
            for (int i = 0; i < 32; ++i) {
                const int h = c * 32 + i;
                p = fmaf(hid[h], Ws2[(size_t)h * NSPECIAL_ + ns], p);
            }
            red[t] = p;
            __syncthreads();
            if (t < NSPECIAL_) {
                float s = bs2[t];
                #pragma unroll
                for (int c2 = 0; c2 < 8; ++c2) s += red[c2 * 32 + t];
                sp[t] = s;
            }
            __syncthreads();
            if (t < SIDX_)
                out[(size_t)m * POL_COLS + L_ + t] = sp[sidx[t]];
        } else {
            if (t < 128) {
                const int np = t & 3, c = t >> 2;
                float p = 0.f;
                #pragma unroll
                for (int i = 0; i < 8; ++i) {
                    const int h = c * 8 + i;
                    p = fmaf(hid[h], Wv2[(size_t)h * NPLAYERS_ + np], p);
                }
                red[t] = p;
            }
            __syncthreads();
            if (t < NPLAYERS_) {
                float s = bv2[t];
                #pragma unroll
                for (int c2 = 0; c2 < 32; ++c2) s += red[c2 * 4 + t];
                out[(size_t)M_ * POL_COLS + (size_t)m * NPLAYERS_ + t] = s;
            }
        }
    }
}

extern "C" void kernel_launch(void* const* d_in, const int* in_sizes, int n_in,
                              void* d_out, int out_size, void* d_ws, size_t ws_size,
                              hipStream_t stream) {
    const float* emb  = (const float*)d_in[0];
    const float* cls  = (const float*)d_in[1];
    const int*   sm   = (const int*)d_in[2];
    const int*   sidx = (const int*)d_in[3];
    const float* Wp   = (const float*)d_in[4];
    const float* bp   = (const float*)d_in[5];
    const float* Wv1  = (const float*)d_in[6];
    const float* bv1  = (const float*)d_in[7];
    const float* Wv2  = (const float*)d_in[8];
    const float* bv2  = (const float*)d_in[9];
    const float* Ws1  = (const float*)d_in[10];
    const float* bs1  = (const float*)d_in[11];
    const float* Ws2  = (const float*)d_in[12];
    const float* bs2  = (const float*)d_in[13];
    float* out = (float*)d_out;
    float* ws  = (float*)d_ws;

    k_build<<<NJOBA, 256, 0, stream>>>(emb, cls, Wp, bp, Ws1, Wv1, ws);
    k_fused2<<<512 + 16, 256, 0, stream>>>(
        sm, ws, sidx, bs1, bv1, Ws2, bs2, Wv2, bv2, out);
}